// Round 8
// baseline (142.362 us; speedup 1.0000x reference)
//
#include <hip/hip_runtime.h>

constexpr int TT   = 8192;   // nb_territories
constexpr int HH   = 4096;   // hidden size
constexpr int NACT = 65536;  // action pairs
constexpr int NTH  = 256;

typedef float f32x4 __attribute__((ext_vector_type(4)));  // native vec for NT stores

// deterministic block-wide sum; returns the same value to ALL threads
__device__ __forceinline__ float block_reduce(float v, float* s, int t)
{
#pragma unroll
    for (int off = 32; off; off >>= 1) v += __shfl_down(v, off, 64);
    if ((t & 63) == 0) s[t >> 6] = v;
    __syncthreads();
    float r = s[0] + s[1] + s[2] + s[3];
    __syncthreads();
    return r;
}

// ---------------------------------------------------------------------------
// K1: x[row] = tanh(Win[row,:] @ p + bin[row])  (row = blockIdx.x, 4096 blocks)
//     + zero-fill 192 MB of out (3072 float4/block, NT stores: don't evict
//       L3-resident weights). Block 0 also re-arms the K3 barrier counter.
// Traffic: 128 MB R + 192 MB W.
// ---------------------------------------------------------------------------
__global__ __launch_bounds__(256) void k_gemv_in_fill(
    const float* __restrict__ W, const float* __restrict__ p,
    const float* __restrict__ b, float* __restrict__ x, float* __restrict__ out,
    unsigned int* __restrict__ counter)
{
    const int row = blockIdx.x;
    const int t   = threadIdx.x;
    if (row == 0 && t == 0) *counter = 0u;   // re-arm barrier for this call

    const float4* __restrict__ Wr = reinterpret_cast<const float4*>(W + (size_t)row * TT);
    const float4* __restrict__ pv = reinterpret_cast<const float4*>(p);
    float acc = 0.f;
#pragma unroll
    for (int i = 0; i < TT / 4 / NTH; ++i) {   // 8 iters
        float4 w = Wr[i * NTH + t];
        float4 q = pv[i * NTH + t];
        acc += w.x * q.x + w.y * q.y + w.z * q.z + w.w * q.w;
    }
    __shared__ float s[4];
    float sum = block_reduce(acc, s, t);
    if (t == 0) x[row] = tanhf(sum + b[row]);

    // zero-fill slice: 3072 float4 = 48 KB per block, 12 per thread
    f32x4* __restrict__ o4 = reinterpret_cast<f32x4*>(out);
    const f32x4 z = {0.f, 0.f, 0.f, 0.f};
    const size_t base = (size_t)row * 3072;
#pragma unroll
    for (int i = 0; i < 12; ++i)
        __builtin_nontemporal_store(z, &o4[base + i * NTH + t]);
}

// ---------------------------------------------------------------------------
// K2: th[r] = tanh([Wo;Wd][r,:] @ x + [bo;bd][r])  (r = blockIdx.x, 16384 blocks)
//     + zero-fill the remaining 64 MB of out (256 float4 per block).
// Traffic: 256 MB R + 64 MB W.
// ---------------------------------------------------------------------------
__global__ __launch_bounds__(256) void k_heads_fill(
    const float* __restrict__ Wo, const float* __restrict__ bo,
    const float* __restrict__ Wd, const float* __restrict__ bd,
    const float* __restrict__ x, float* __restrict__ th, float* __restrict__ out)
{
    const int r = blockIdx.x;
    const int t = threadIdx.x;
    const float* W; const float* bb; int rr;
    if (r < TT) { W = Wo; bb = bo; rr = r; }
    else        { W = Wd; bb = bd; rr = r - TT; }
    const float4* __restrict__ Wr = reinterpret_cast<const float4*>(W + (size_t)rr * HH);
    const float4* __restrict__ xv = reinterpret_cast<const float4*>(x);
    float acc = 0.f;
#pragma unroll
    for (int i = 0; i < HH / 4 / NTH; ++i) {   // 4 iters
        float4 w = Wr[i * NTH + t];
        float4 q = xv[i * NTH + t];
        acc += w.x * q.x + w.y * q.y + w.z * q.z + w.w * q.w;
    }
    __shared__ float s[4];
    float sum = block_reduce(acc, s, t);
    if (t == 0) th[r] = tanhf(sum + bb[rr]);

    // zero-fill slice: float4 indices [12582912 + r*256, +256)
    f32x4* __restrict__ o4 = reinterpret_cast<f32x4*>(out);
    const f32x4 z = {0.f, 0.f, 0.f, 0.f};
    __builtin_nontemporal_store(z, &o4[12582912 + (size_t)r * NTH + t]);
}

// ---------------------------------------------------------------------------
// K3 (merged scatter+finalize, 256 blocks -- one per CU, all co-resident):
//  a) u = exp(torig[o]*tdest[d] - 1); claim zeroed slot via atomicExch;
//     unique claimant contributes u to the block partial.
//     (exp(-1000-m)==0 in fp32 => all non-action softmax entries are exactly
//      0; shift m'=1 is valid by shift-invariance since v<=1.)
//  b) publish partial (agent release) + counter arrive; thread 0 spins until
//     all gridDim.x partials posted (acquire).
//  c) every block deterministically reduces all partials -> identical invZ;
//     write out = u*invZ (idempotent across duplicate actions).
// ---------------------------------------------------------------------------
__global__ __launch_bounds__(256) void k_scatter_finalize(
    const int* __restrict__ pa, const float* __restrict__ th,
    float* __restrict__ out, float* __restrict__ partial,
    unsigned int* __restrict__ counter)
{
    const int b = blockIdx.x;
    const int t = threadIdx.x;
    const int i = b * NTH + t;
    const int o = pa[2 * i];
    const int d = pa[2 * i + 1];
    float* slot = out + ((size_t)o * TT + d);
    const float v = th[o] * th[TT + d];
    const float u = expf(v - 1.0f);
    float old = atomicExch(slot, u);
    float c = (old == 0.0f) ? u : 0.0f;

    __shared__ float s[4];
    float bc = block_reduce(c, s, t);

    if (t == 0) {
        __hip_atomic_store(&partial[b], bc, __ATOMIC_RELEASE, __HIP_MEMORY_SCOPE_AGENT);
        __atomic_fetch_add(counter, 1u, __ATOMIC_ACQ_REL);
        while (__hip_atomic_load(counter, __ATOMIC_ACQUIRE, __HIP_MEMORY_SCOPE_AGENT)
               < (unsigned)gridDim.x)
            __builtin_amdgcn_s_sleep(8);
    }
    __syncthreads();   // all threads ordered after thread 0's acquire

    // deterministic redundant reduce of all 256 partials (atomic loads:
    // coherent path across XCD L2s; order fixed -> bit-identical invZ)
    float ps = __hip_atomic_load(&partial[t], __ATOMIC_RELAXED, __HIP_MEMORY_SCOPE_AGENT);
    const float invZ = 1.0f / block_reduce(ps, s, t);
    *slot = u * invZ;
}

// ---------------------------------------------------------------------------
extern "C" void kernel_launch(void* const* d_in, const int* in_sizes, int n_in,
                              void* d_out, int out_size, void* d_ws, size_t ws_size,
                              hipStream_t stream)
{
    const int*   pa  = (const int*)  d_in[0];  // possible_actions [NACT,2] int32
    const float* p   = (const float*)d_in[1];  // presence [TT]
    const float* Win = (const float*)d_in[2];  // [HH,TT]
    const float* bin = (const float*)d_in[3];  // [HH]
    const float* Wo  = (const float*)d_in[4];  // [TT,HH]
    const float* bo  = (const float*)d_in[5];  // [TT]
    const float* Wd  = (const float*)d_in[6];  // [TT,HH]
    const float* bd  = (const float*)d_in[7];  // [TT]
    float* out = (float*)d_out;

    float*        x       = (float*)d_ws;      // [HH]
    float*        th      = x + HH;            // [2*TT]
    float*        partial = th + 2 * TT;       // [256]
    unsigned int* counter = (unsigned int*)(partial + 256);

    k_gemv_in_fill    <<<HH,         NTH, 0, stream>>>(Win, p, bin, x, out, counter);
    k_heads_fill      <<<2 * TT,     NTH, 0, stream>>>(Wo, bo, Wd, bd, x, th, out);
    k_scatter_finalize<<<NACT / NTH, NTH, 0, stream>>>(pa, th, out, partial, counter);
}

// Round 9
// 131.724 us; speedup vs baseline: 1.0808x; 1.0808x over previous
//
#include <hip/hip_runtime.h>

constexpr int TT   = 8192;   // nb_territories
constexpr int HH   = 4096;   // hidden size
constexpr int NACT = 65536;  // action pairs
constexpr int NTH  = 256;

typedef float f32x4 __attribute__((ext_vector_type(4)));  // native vec for NT stores

// deterministic block-wide sum; returns the same value to ALL threads
__device__ __forceinline__ float block_reduce(float v, float* s, int t)
{
#pragma unroll
    for (int off = 32; off; off >>= 1) v += __shfl_down(v, off, 64);
    if ((t & 63) == 0) s[t >> 6] = v;
    __syncthreads();
    float r = s[0] + s[1] + s[2] + s[3];
    __syncthreads();
    return r;
}

// ---------------------------------------------------------------------------
// K1 (identical to R6 best): x[row] = tanh(Win[row,:] @ p + bin[row]),
// row = blockIdx.x (4096 blocks); then zero-fill 192 MB of out
// (3072 float4/block, NT so the dead zero stream doesn't evict L3 weights).
// Traffic: 128 MB R + 192 MB W.
// ---------------------------------------------------------------------------
__global__ __launch_bounds__(256) void k_gemv_in_fill(
    const float* __restrict__ W, const float* __restrict__ p,
    const float* __restrict__ b, float* __restrict__ x, float* __restrict__ out)
{
    const int row = blockIdx.x;
    const int t   = threadIdx.x;
    const float4* __restrict__ Wr = reinterpret_cast<const float4*>(W + (size_t)row * TT);
    const float4* __restrict__ pv = reinterpret_cast<const float4*>(p);
    float acc = 0.f;
#pragma unroll
    for (int i = 0; i < TT / 4 / NTH; ++i) {   // 8 iters
        float4 w = Wr[i * NTH + t];
        float4 q = pv[i * NTH + t];
        acc += w.x * q.x + w.y * q.y + w.z * q.z + w.w * q.w;
    }
    __shared__ float s[4];
    float sum = block_reduce(acc, s, t);
    if (t == 0) x[row] = tanhf(sum + b[row]);

    // zero-fill slice: 3072 float4 = 48 KB per block, 12 per thread
    f32x4* __restrict__ o4 = reinterpret_cast<f32x4*>(out);
    const f32x4 z = {0.f, 0.f, 0.f, 0.f};
    const size_t base = (size_t)row * 3072;
#pragma unroll
    for (int i = 0; i < 12; ++i)
        __builtin_nontemporal_store(z, &o4[base + i * NTH + t]);
}

// ---------------------------------------------------------------------------
// K2 (the ONE change vs R6): 4 rows/block (4096 blocks).
// th[base..base+3] = tanh([Wo;Wd][rows,:] @ x + b[rows]); x chunk loaded once
// and reused x4; 4 independent accumulator chains (ILP); store-after-reduce
// order kept from R6. Then zero-fill the remaining 64 MB (1024 float4/block).
// Traffic: 256 MB R + 64 MB W.
// ---------------------------------------------------------------------------
__global__ __launch_bounds__(256) void k_heads_fill(
    const float* __restrict__ Wo, const float* __restrict__ bo,
    const float* __restrict__ Wd, const float* __restrict__ bd,
    const float* __restrict__ x, float* __restrict__ th, float* __restrict__ out)
{
    const int blk  = blockIdx.x;           // 0..4095
    const int t    = threadIdx.x;
    const int base = blk * 4;              // 4 consecutive rows, same head

    const float* W; const float* bb; int rr;
    if (base < TT) { W = Wo; bb = bo; rr = base; }
    else           { W = Wd; bb = bd; rr = base - TT; }
    const float4* __restrict__ xv = reinterpret_cast<const float4*>(x);
    const float4* __restrict__ W0 = reinterpret_cast<const float4*>(W + (size_t)(rr + 0) * HH);
    const float4* __restrict__ W1 = reinterpret_cast<const float4*>(W + (size_t)(rr + 1) * HH);
    const float4* __restrict__ W2 = reinterpret_cast<const float4*>(W + (size_t)(rr + 2) * HH);
    const float4* __restrict__ W3 = reinterpret_cast<const float4*>(W + (size_t)(rr + 3) * HH);

    float a0 = 0.f, a1 = 0.f, a2 = 0.f, a3 = 0.f;
#pragma unroll
    for (int i = 0; i < HH / 4 / NTH; ++i) {             // 4 iters
        const int idx = i * NTH + t;
        float4 q  = xv[idx];
        float4 w0 = W0[idx];
        float4 w1 = W1[idx];
        float4 w2 = W2[idx];
        float4 w3 = W3[idx];
        a0 += w0.x * q.x + w0.y * q.y + w0.z * q.z + w0.w * q.w;
        a1 += w1.x * q.x + w1.y * q.y + w1.z * q.z + w1.w * q.w;
        a2 += w2.x * q.x + w2.y * q.y + w2.z * q.z + w2.w * q.w;
        a3 += w3.x * q.x + w3.y * q.y + w3.z * q.z + w3.w * q.w;
    }

    __shared__ float s[4][4];
#pragma unroll
    for (int off = 32; off; off >>= 1) {
        a0 += __shfl_down(a0, off, 64);
        a1 += __shfl_down(a1, off, 64);
        a2 += __shfl_down(a2, off, 64);
        a3 += __shfl_down(a3, off, 64);
    }
    if ((t & 63) == 0) {
        const int w = t >> 6;
        s[w][0] = a0; s[w][1] = a1; s[w][2] = a2; s[w][3] = a3;
    }
    __syncthreads();
    if (t < 4)
        th[base + t] = tanhf(s[0][t] + s[1][t] + s[2][t] + s[3][t] + bb[rr + t]);

    // zero-fill slice after compute (R6 ordering): 1024 float4/block
    f32x4* __restrict__ o4 = reinterpret_cast<f32x4*>(out);
    const f32x4 z = {0.f, 0.f, 0.f, 0.f};
    const size_t fb = 12582912 + (size_t)blk * 1024;
#pragma unroll
    for (int i = 0; i < 4; ++i)
        __builtin_nontemporal_store(z, &o4[fb + i * NTH + t]);
}

// ---------------------------------------------------------------------------
// K3: u = exp(torig[o]*tdest[d] - 1); claim zeroed slot via atomicExch; the
// unique claimant adds u to the block partial. (exp(-1000-m)==0 in fp32 =>
// all non-action softmax entries are exactly 0; shift m'=1 valid since v<=1.)
// ---------------------------------------------------------------------------
__global__ __launch_bounds__(256) void k_scatter(
    const int* __restrict__ pa, const float* __restrict__ th,
    float* __restrict__ out, float* __restrict__ partial)
{
    const int i = blockIdx.x * NTH + threadIdx.x;
    const int o = pa[2 * i];
    const int d = pa[2 * i + 1];
    const float v = th[o] * th[TT + d];
    const float u = expf(v - 1.0f);
    float old = atomicExch(out + ((size_t)o * TT + d), u);
    float c = (old == 0.0f) ? u : 0.0f;
    __shared__ float s[4];
    float bc = block_reduce(c, s, threadIdx.x);
    if (threadIdx.x == 0) partial[blockIdx.x] = bc;
}

// ---------------------------------------------------------------------------
// K4: every block deterministically reduces the 256 partials -> invZ; write
// out = u * invZ (idempotent across duplicate actions).
// ---------------------------------------------------------------------------
__global__ __launch_bounds__(256) void k_finalize(
    const int* __restrict__ pa, const float* __restrict__ th,
    const float* __restrict__ partial, float* __restrict__ out)
{
    __shared__ float s[4];
    const float invZ = 1.0f / block_reduce(partial[threadIdx.x], s, threadIdx.x);
    const int i = blockIdx.x * NTH + threadIdx.x;
    const int o = pa[2 * i];
    const int d = pa[2 * i + 1];
    const float v = th[o] * th[TT + d];
    out[(size_t)o * TT + d] = expf(v - 1.0f) * invZ;
}

// ---------------------------------------------------------------------------
extern "C" void kernel_launch(void* const* d_in, const int* in_sizes, int n_in,
                              void* d_out, int out_size, void* d_ws, size_t ws_size,
                              hipStream_t stream)
{
    const int*   pa  = (const int*)  d_in[0];  // possible_actions [NACT,2] int32
    const float* p   = (const float*)d_in[1];  // presence [TT]
    const float* Win = (const float*)d_in[2];  // [HH,TT]
    const float* bin = (const float*)d_in[3];  // [HH]
    const float* Wo  = (const float*)d_in[4];  // [TT,HH]
    const float* bo  = (const float*)d_in[5];  // [TT]
    const float* Wd  = (const float*)d_in[6];  // [TT,HH]
    const float* bd  = (const float*)d_in[7];  // [TT]
    float* out = (float*)d_out;

    float* x       = (float*)d_ws;        // [HH]
    float* th      = x + HH;              // [2*TT]
    float* partial = th + 2 * TT;         // [256]

    k_gemv_in_fill<<<HH,           NTH, 0, stream>>>(Win, p, bin, x, out);
    k_heads_fill  <<<(2 * TT) / 4, NTH, 0, stream>>>(Wo, bo, Wd, bd, x, th, out);
    k_scatter     <<<NACT / NTH,   NTH, 0, stream>>>(pa, th, out, partial);
    k_finalize    <<<NACT / NTH,   NTH, 0, stream>>>(pa, th, partial, out);
}

// Round 10
// 128.397 us; speedup vs baseline: 1.1088x; 1.0259x over previous
//
#include <hip/hip_runtime.h>

constexpr int TT   = 8192;   // nb_territories
constexpr int HH   = 4096;   // hidden size
constexpr int NACT = 65536;  // action pairs
constexpr int NTH  = 256;

typedef float f32x4 __attribute__((ext_vector_type(4)));  // native vec for NT stores

// deterministic block-wide sum; returns the same value to ALL threads
__device__ __forceinline__ float block_reduce(float v, float* s, int t)
{
#pragma unroll
    for (int off = 32; off; off >>= 1) v += __shfl_down(v, off, 64);
    if ((t & 63) == 0) s[t >> 6] = v;
    __syncthreads();
    float r = s[0] + s[1] + s[2] + s[3];
    __syncthreads();
    return r;
}

// ---------------------------------------------------------------------------
// K1: x[row] = tanh(Win[row,:] @ p + bin[row])  (row = blockIdx.x, 4096 blocks)
//     + zero-fill 192 MB of out (3072 float4 per block, NT stores so the dead
//       zero stream doesn't evict L3-resident weights).
// Traffic: 128 MB R + 192 MB W.
// ---------------------------------------------------------------------------
__global__ __launch_bounds__(256) void k_gemv_in_fill(
    const float* __restrict__ W, const float* __restrict__ p,
    const float* __restrict__ b, float* __restrict__ x, float* __restrict__ out)
{
    const int row = blockIdx.x;
    const int t   = threadIdx.x;
    const float4* __restrict__ Wr = reinterpret_cast<const float4*>(W + (size_t)row * TT);
    const float4* __restrict__ pv = reinterpret_cast<const float4*>(p);
    float acc = 0.f;
#pragma unroll
    for (int i = 0; i < TT / 4 / NTH; ++i) {   // 8 iters
        float4 w = Wr[i * NTH + t];
        float4 q = pv[i * NTH + t];
        acc += w.x * q.x + w.y * q.y + w.z * q.z + w.w * q.w;
    }
    __shared__ float s[4];
    float sum = block_reduce(acc, s, t);
    if (t == 0) x[row] = tanhf(sum + b[row]);

    // zero-fill slice: 3072 float4 = 48 KB per block, 12 per thread
    f32x4* __restrict__ o4 = reinterpret_cast<f32x4*>(out);
    const f32x4 z = {0.f, 0.f, 0.f, 0.f};
    const size_t base = (size_t)row * 3072;
#pragma unroll
    for (int i = 0; i < 12; ++i)
        __builtin_nontemporal_store(z, &o4[base + i * NTH + t]);
}

// ---------------------------------------------------------------------------
// K2: th[r] = tanh([Wo;Wd][r,:] @ x + [bo;bd][r])  (r = blockIdx.x, 16384 blocks)
//     + zero-fill the remaining 64 MB of out (256 float4 per block).
// Traffic: 256 MB R + 64 MB W.
// ---------------------------------------------------------------------------
__global__ __launch_bounds__(256) void k_heads_fill(
    const float* __restrict__ Wo, const float* __restrict__ bo,
    const float* __restrict__ Wd, const float* __restrict__ bd,
    const float* __restrict__ x, float* __restrict__ th, float* __restrict__ out)
{
    const int r = blockIdx.x;
    const int t = threadIdx.x;
    const float* W; const float* bb; int rr;
    if (r < TT) { W = Wo; bb = bo; rr = r; }
    else        { W = Wd; bb = bd; rr = r - TT; }
    const float4* __restrict__ Wr = reinterpret_cast<const float4*>(W + (size_t)rr * HH);
    const float4* __restrict__ xv = reinterpret_cast<const float4*>(x);
    float acc = 0.f;
#pragma unroll
    for (int i = 0; i < HH / 4 / NTH; ++i) {   // 4 iters
        float4 w = Wr[i * NTH + t];
        float4 q = xv[i * NTH + t];
        acc += w.x * q.x + w.y * q.y + w.z * q.z + w.w * q.w;
    }
    __shared__ float s[4];
    float sum = block_reduce(acc, s, t);
    if (t == 0) th[r] = tanhf(sum + bb[rr]);

    // zero-fill slice: float4 indices [12582912 + r*256, +256)
    f32x4* __restrict__ o4 = reinterpret_cast<f32x4*>(out);
    const f32x4 z = {0.f, 0.f, 0.f, 0.f};
    __builtin_nontemporal_store(z, &o4[12582912 + (size_t)r * NTH + t]);
}

// ---------------------------------------------------------------------------
// K3: u = exp(torig[o]*tdest[d] - 1); claim zeroed slot via atomicExch; the
// unique claimant adds u to the block partial. (exp(-1000-m)==0 in fp32 =>
// all non-action softmax entries are exactly 0; shift m'=1 valid since v<=1.)
// ---------------------------------------------------------------------------
__global__ __launch_bounds__(256) void k_scatter(
    const int* __restrict__ pa, const float* __restrict__ th,
    float* __restrict__ out, float* __restrict__ partial)
{
    const int i = blockIdx.x * NTH + threadIdx.x;
    const int o = pa[2 * i];
    const int d = pa[2 * i + 1];
    const float v = th[o] * th[TT + d];
    const float u = expf(v - 1.0f);
    float old = atomicExch(out + ((size_t)o * TT + d), u);
    float c = (old == 0.0f) ? u : 0.0f;
    __shared__ float s[4];
    float bc = block_reduce(c, s, threadIdx.x);
    if (threadIdx.x == 0) partial[blockIdx.x] = bc;
}

// ---------------------------------------------------------------------------
// K4: every block deterministically reduces the 256 partials -> invZ; write
// out = u * invZ (idempotent across duplicate actions).
// ---------------------------------------------------------------------------
__global__ __launch_bounds__(256) void k_finalize(
    const int* __restrict__ pa, const float* __restrict__ th,
    const float* __restrict__ partial, float* __restrict__ out)
{
    __shared__ float s[4];
    const float invZ = 1.0f / block_reduce(partial[threadIdx.x], s, threadIdx.x);
    const int i = blockIdx.x * NTH + threadIdx.x;
    const int o = pa[2 * i];
    const int d = pa[2 * i + 1];
    const float v = th[o] * th[TT + d];
    out[(size_t)o * TT + d] = expf(v - 1.0f) * invZ;
}

// ---------------------------------------------------------------------------
extern "C" void kernel_launch(void* const* d_in, const int* in_sizes, int n_in,
                              void* d_out, int out_size, void* d_ws, size_t ws_size,
                              hipStream_t stream)
{
    const int*   pa  = (const int*)  d_in[0];  // possible_actions [NACT,2] int32
    const float* p   = (const float*)d_in[1];  // presence [TT]
    const float* Win = (const float*)d_in[2];  // [HH,TT]
    const float* bin = (const float*)d_in[3];  // [HH]
    const float* Wo  = (const float*)d_in[4];  // [TT,HH]
    const float* bo  = (const float*)d_in[5];  // [TT]
    const float* Wd  = (const float*)d_in[6];  // [TT,HH]
    const float* bd  = (const float*)d_in[7];  // [TT]
    float* out = (float*)d_out;

    float* x       = (float*)d_ws;        // [HH]
    float* th      = x + HH;              // [2*TT]
    float* partial = th + 2 * TT;         // [256]

    k_gemv_in_fill<<<HH,         NTH, 0, stream>>>(Win, p, bin, x, out);
    k_heads_fill  <<<2 * TT,     NTH, 0, stream>>>(Wo, bo, Wd, bd, x, th, out);
    k_scatter     <<<NACT / NTH, NTH, 0, stream>>>(pa, th, out, partial);
    k_finalize    <<<NACT / NTH, NTH, 0, stream>>>(pa, th, partial, out);
}